// Round 1
// baseline (6473.580 us; speedup 1.0000x reference)
//
#include <hip/hip_runtime.h>
#include <hip/hip_fp16.h>

#define NPT 4096
#define DM 128
#define FINF __builtin_huge_valf()

static __device__ __forceinline__ unsigned long long umin64(unsigned long long a, unsigned long long b) {
    return a < b ? a : b;
}

// ---------------- pairwise distance: D[mat][i][j] = sqrt(sum_k (x_i-x_j)^2 + 1e-12), fp16 ----------------
__global__ __launch_bounds__(256) void dist_kernel(const float* __restrict__ x1,
                                                   const float* __restrict__ x2,
                                                   __half* __restrict__ Dall) {
    const int mat = blockIdx.z;
    const float* __restrict__ x = mat ? x2 : x1;
    __half* __restrict__ D = Dall + (size_t)mat * NPT * NPT;

    __shared__ float As[64 * 68];
    __shared__ float Bs[64 * 68];

    const int t = threadIdx.x;
    const int rowBase = blockIdx.y * 64;
    const int colBase = blockIdx.x * 64;
    const int m0 = (t >> 4) * 4;
    const int n0 = (t & 15) * 4;

    float acc[4][4] = {};

    for (int kk = 0; kk < DM; kk += 64) {
        // stage 64x64 half-tiles of A-rows and B-rows
        for (int q = 0; q < 4; ++q) {
            int fi = t + q * 256;          // 0..1023
            int r = fi >> 4;               // 0..63
            int c = fi & 15;               // float4 index 0..15
            *(float4*)(As + r * 68 + c * 4) =
                *(const float4*)(x + (size_t)(rowBase + r) * DM + kk + c * 4);
            *(float4*)(Bs + r * 68 + c * 4) =
                *(const float4*)(x + (size_t)(colBase + r) * DM + kk + c * 4);
        }
        __syncthreads();

        for (int k = 0; k < 64; k += 4) {
            float4 a[4], b[4];
            #pragma unroll
            for (int m = 0; m < 4; ++m) a[m] = *(const float4*)(As + (m0 + m) * 68 + k);
            #pragma unroll
            for (int n = 0; n < 4; ++n) b[n] = *(const float4*)(Bs + (n0 + n) * 68 + k);
            #pragma unroll
            for (int m = 0; m < 4; ++m)
                #pragma unroll
                for (int n = 0; n < 4; ++n) {
                    float d0 = a[m].x - b[n].x;
                    float d1 = a[m].y - b[n].y;
                    float d2 = a[m].z - b[n].z;
                    float d3 = a[m].w - b[n].w;
                    acc[m][n] += d0 * d0 + d1 * d1 + d2 * d2 + d3 * d3;
                }
        }
        __syncthreads();
    }

    #pragma unroll
    for (int m = 0; m < 4; ++m)
        #pragma unroll
        for (int n = 0; n < 4; ++n) {
            float d = sqrtf(acc[m][n] + 1e-12f);
            D[(size_t)(rowBase + m0 + m) * NPT + (colBase + n0 + n)] = __float2half(d);
        }
}

// ---------------- Prim's MST: one block per matrix, dist[] in registers ----------------
__global__ __launch_bounds__(1024) void prim_kernel(const __half* __restrict__ Dall,
                                                    float* __restrict__ wout) {
    const int mat = blockIdx.x;
    const __half* __restrict__ D = Dall + (size_t)mat * NPT * NPT;
    float* __restrict__ w = wout + (size_t)mat * NPT;

    const int t = threadIdx.x;
    const int wv = t >> 6, ln = t & 63;
    __shared__ unsigned long long red[32];

    float dist[4];
    #pragma unroll
    for (int k = 0; k < 4; ++k) dist[k] = __half2float(D[t + k * 1024]);
    if (t == 0) dist[0] = FINF;   // node 0 starts in tree

    for (int it = 0; it < NPT - 1; ++it) {
        // local argmin over this thread's 4 entries, packed key = (f32 bits << 32) | index
        unsigned long long best = 0xffffffffffffffffull;
        #pragma unroll
        for (int k = 0; k < 4; ++k) {
            unsigned long long key =
                ((unsigned long long)__float_as_uint(dist[k]) << 32) | (unsigned)(t + k * 1024);
            best = umin64(best, key);
        }
        // wave reduce (64 lanes)
        #pragma unroll
        for (int off = 32; off > 0; off >>= 1)
            best = umin64(best, __shfl_down(best, off));
        if (ln == 0) red[wv] = best;
        __syncthreads();
        // cross-wave reduce (16 waves) by wave 0
        if (wv == 0) {
            unsigned long long b2 = (ln < 16) ? red[ln] : 0xffffffffffffffffull;
            #pragma unroll
            for (int off = 8; off > 0; off >>= 1)
                b2 = umin64(b2, __shfl_down(b2, off));
            if (ln == 0) red[16] = b2;
        }
        __syncthreads();

        unsigned long long kbest = red[16];
        const int j = (int)(unsigned)kbest;
        if (t == 0) {
            float wsel = __uint_as_float((unsigned)(kbest >> 32));
            w[it] = fminf(wsel, 100.0f);   // filtration cap
        }

        // dist = min(dist, D[j]); mark j as in-tree
        const __half* __restrict__ row = D + (size_t)j * NPT;
        __half h[4];
        #pragma unroll
        for (int k = 0; k < 4; ++k) h[k] = row[t + k * 1024];
        #pragma unroll
        for (int k = 0; k < 4; ++k) {
            int e = t + k * 1024;
            if (e == j) dist[k] = FINF;
            else if (dist[k] != FINF) dist[k] = fminf(dist[k], __half2float(h[k]));
        }
    }
    if (t == 0) w[NPT - 1] = 0.0f;   // pad slot (sorts to front, contributes 0)
}

// ---------------- representation loss partial sums ----------------
__global__ void zero_kernel(float* acc) { acc[0] = 0.0f; }

__global__ __launch_bounds__(256) void rep_kernel(const float4* __restrict__ x1,
                                                  const float4* __restrict__ x2,
                                                  float* __restrict__ acc) {
    int idx = blockIdx.x * blockDim.x + threadIdx.x;
    int stride = gridDim.x * blockDim.x;
    float s = 0.f;
    for (int i = idx; i < NPT * DM / 4; i += stride) {
        float4 a = x1[i], b = x2[i];
        float d0 = a.x - b.x, d1 = a.y - b.y, d2 = a.z - b.z, d3 = a.w - b.w;
        s += d0 * d0 + d1 * d1 + d2 * d2 + d3 * d3;
    }
    #pragma unroll
    for (int off = 32; off > 0; off >>= 1) s += __shfl_down(s, off);
    __shared__ float partial[4];
    int wv = threadIdx.x >> 6, ln = threadIdx.x & 63;
    if (ln == 0) partial[wv] = s;
    __syncthreads();
    if (threadIdx.x == 0) {
        float tot = partial[0] + partial[1] + partial[2] + partial[3];
        atomicAdd(acc, tot);
    }
}

// ---------------- sort both weight arrays (bitonic, LDS), W1 + combine ----------------
__global__ __launch_bounds__(1024) void final_kernel(const float* __restrict__ w1,
                                                     const float* __restrict__ w2,
                                                     const float* __restrict__ rep,
                                                     float* __restrict__ out) {
    __shared__ float s1[NPT];
    __shared__ float s2[NPT];
    const int t = threadIdx.x;
    for (int i = t; i < NPT; i += 1024) { s1[i] = w1[i]; s2[i] = w2[i]; }
    __syncthreads();

    for (int k = 2; k <= NPT; k <<= 1) {
        for (int j = k >> 1; j > 0; j >>= 1) {
            for (int i = t; i < NPT; i += 1024) {
                int ixj = i ^ j;
                if (ixj > i) {
                    bool up = (i & k) == 0;
                    float a = s1[i], b = s1[ixj];
                    if ((a > b) == up) { s1[i] = b; s1[ixj] = a; }
                    float c = s2[i], d = s2[ixj];
                    if ((c > d) == up) { s2[i] = d; s2[ixj] = c; }
                }
            }
            __syncthreads();
        }
    }

    float loc = 0.f;
    for (int i = t; i < NPT; i += 1024) loc += fabsf(s1[i] - s2[i]);
    #pragma unroll
    for (int off = 32; off > 0; off >>= 1) loc += __shfl_down(loc, off);
    __shared__ float reds[16];
    int wv = t >> 6, ln = t & 63;
    if (ln == 0) reds[wv] = loc;
    __syncthreads();
    if (t == 0) {
        float tot = 0.f;
        #pragma unroll
        for (int i = 0; i < 16; ++i) tot += reds[i];
        out[0] = tot + rep[0] * (1.0f / (NPT * DM));
    }
}

extern "C" void kernel_launch(void* const* d_in, const int* in_sizes, int n_in,
                              void* d_out, int out_size, void* d_ws, size_t ws_size,
                              hipStream_t stream) {
    const float* x1 = (const float*)d_in[0];
    const float* x2 = (const float*)d_in[1];
    float* out = (float*)d_out;

    char* ws = (char*)d_ws;
    __half* D = (__half*)ws;                                  // 2 * 4096*4096 * 2B = 64 MB
    float* w1 = (float*)(ws + (size_t)2 * NPT * NPT * sizeof(__half));
    float* w2 = w1 + NPT;
    float* rep = w2 + NPT;

    zero_kernel<<<1, 1, 0, stream>>>(rep);

    dim3 dg(NPT / 64, NPT / 64, 2);
    dist_kernel<<<dg, 256, 0, stream>>>(x1, x2, D);

    prim_kernel<<<2, 1024, 0, stream>>>(D, w1);

    rep_kernel<<<256, 256, 0, stream>>>((const float4*)x1, (const float4*)x2, rep);

    final_kernel<<<1, 1024, 0, stream>>>(w1, w2, rep, out);
}

// Round 2
// 647.380 us; speedup vs baseline: 9.9997x; 9.9997x over previous
//
#include <hip/hip_runtime.h>
#include <hip/hip_fp16.h>

#define NPT 4096
#define DM 128
#define ROUNDS 12
#define INF64 0xFFFFFFFFFFFFFFFFull

// ---------------- pairwise distance: D[mat][i][j] = sqrt(sum_k (x_i-x_j)^2 + 1e-12), fp16 ----------------
__global__ __launch_bounds__(256) void dist_kernel(const float* __restrict__ x1,
                                                   const float* __restrict__ x2,
                                                   __half* __restrict__ Dall) {
    const int mat = blockIdx.z;
    const float* __restrict__ x = mat ? x2 : x1;
    __half* __restrict__ D = Dall + (size_t)mat * NPT * NPT;

    __shared__ float As[64 * 68];
    __shared__ float Bs[64 * 68];

    const int t = threadIdx.x;
    const int rowBase = blockIdx.y * 64;
    const int colBase = blockIdx.x * 64;
    const int m0 = (t >> 4) * 4;
    const int n0 = (t & 15) * 4;

    float acc[4][4] = {};

    for (int kk = 0; kk < DM; kk += 64) {
        for (int q = 0; q < 4; ++q) {
            int fi = t + q * 256;
            int r = fi >> 4;
            int c = fi & 15;
            *(float4*)(As + r * 68 + c * 4) =
                *(const float4*)(x + (size_t)(rowBase + r) * DM + kk + c * 4);
            *(float4*)(Bs + r * 68 + c * 4) =
                *(const float4*)(x + (size_t)(colBase + r) * DM + kk + c * 4);
        }
        __syncthreads();

        for (int k = 0; k < 64; k += 4) {
            float4 a[4], b[4];
            #pragma unroll
            for (int m = 0; m < 4; ++m) a[m] = *(const float4*)(As + (m0 + m) * 68 + k);
            #pragma unroll
            for (int n = 0; n < 4; ++n) b[n] = *(const float4*)(Bs + (n0 + n) * 68 + k);
            #pragma unroll
            for (int m = 0; m < 4; ++m)
                #pragma unroll
                for (int n = 0; n < 4; ++n) {
                    float d0 = a[m].x - b[n].x;
                    float d1 = a[m].y - b[n].y;
                    float d2 = a[m].z - b[n].z;
                    float d3 = a[m].w - b[n].w;
                    acc[m][n] += d0 * d0 + d1 * d1 + d2 * d2 + d3 * d3;
                }
        }
        __syncthreads();
    }

    #pragma unroll
    for (int m = 0; m < 4; ++m)
        #pragma unroll
        for (int n = 0; n < 4; ++n) {
            float d = sqrtf(acc[m][n] + 1e-12f);
            D[(size_t)(rowBase + m0 + m) * NPT + (colBase + n0 + n)] = __float2half(d);
        }
}

// ---------------- init: comp[i]=i, compbest=INF, w=0, cnt=0, rep=0 ----------------
__global__ __launch_bounds__(256) void init_kernel(unsigned* __restrict__ comp,
                                                   unsigned long long* __restrict__ compbest,
                                                   float* __restrict__ w,
                                                   unsigned* __restrict__ cnt,
                                                   float* __restrict__ rep) {
    int i = blockIdx.x * blockDim.x + threadIdx.x;   // 0..8191
    comp[i] = (unsigned)(i & (NPT - 1));
    compbest[i] = INF64;
    w[i] = 0.0f;
    if (i < 2) cnt[i] = 0u;
    if (i == 0) rep[0] = 0.0f;
}

// ---------------- Boruvka phase A: per-node min outgoing edge, atomicMin into component slot ----------------
// block = 1024 (16 waves), each wave handles one node; grid (NPT/16, 2)
__global__ __launch_bounds__(1024) void boruvka_a(const __half* __restrict__ Dall,
                                                  const unsigned* __restrict__ compAll,
                                                  unsigned long long* __restrict__ compbestAll) {
    const int mat = blockIdx.y;
    const __half* __restrict__ D = Dall + (size_t)mat * NPT * NPT;
    const unsigned* __restrict__ comp = compAll + mat * NPT;
    unsigned long long* __restrict__ compbest = compbestAll + mat * NPT;

    __shared__ unsigned short lcomp[NPT];
    const int t = threadIdx.x;
    for (int i = t; i < NPT; i += 1024) lcomp[i] = (unsigned short)comp[i];
    __syncthreads();

    const int wv = t >> 6, ln = t & 63;
    const int node = blockIdx.x * 16 + wv;
    const unsigned ci = lcomp[node];
    const unsigned* __restrict__ row = (const unsigned*)(D + (size_t)node * NPT);

    unsigned best = 0xFFFFFFFFu;
    #pragma unroll
    for (int k = 0; k < 8; ++k) {
        const int jb = k * 512 + ln * 8;                  // 8 consecutive elements
        uint4 dv = *(const uint4*)(row + (jb >> 1));      // 8 halves
        uint4 cv = *(const uint4*)&lcomp[jb];             // 8 u16 comps
        const unsigned dp[4] = {dv.x, dv.y, dv.z, dv.w};
        const unsigned cp[4] = {cv.x, cv.y, cv.z, cv.w};
        #pragma unroll
        for (int q = 0; q < 4; ++q) {
            int j0 = jb + q * 2;
            unsigned k0 = (dp[q] << 16) | (unsigned)j0;
            unsigned k1 = (dp[q] & 0xFFFF0000u) | (unsigned)(j0 + 1);
            if ((cp[q] & 0xFFFFu) == ci) k0 = 0xFFFFFFFFu;
            if ((cp[q] >> 16) == ci)     k1 = 0xFFFFFFFFu;
            unsigned m = k0 < k1 ? k0 : k1;
            best = best < m ? best : m;
        }
    }
    #pragma unroll
    for (int off = 32; off > 0; off >>= 1) {
        unsigned o = __shfl_down(best, off);
        best = best < o ? best : o;
    }
    if (ln == 0 && best != 0xFFFFFFFFu) {
        unsigned h = best >> 16;
        unsigned j = best & 0xFFFFu;
        unsigned mn = (unsigned)node < j ? (unsigned)node : j;
        unsigned mx = (unsigned)node < j ? j : (unsigned)node;
        unsigned long long key64 = ((unsigned long long)h << 48) |
                                   ((unsigned long long)mn << 32) |
                                   ((unsigned long long)mx << 16) |
                                   (unsigned long long)j;
        atomicMin(&compbest[ci], key64);
    }
}

// ---------------- Boruvka phase C+D: union roots, collect edge weights, pointer-jump, compress, reset ----------------
// one block per matrix
__global__ __launch_bounds__(1024) void boruvka_cd(unsigned* __restrict__ compAll,
                                                   unsigned long long* __restrict__ compbestAll,
                                                   float* __restrict__ wAll,
                                                   unsigned* __restrict__ cntAll) {
    const int mat = blockIdx.x;
    unsigned* __restrict__ comp = compAll + mat * NPT;
    unsigned long long* __restrict__ compbest = compbestAll + mat * NPT;
    float* __restrict__ w = wAll + mat * NPT;
    unsigned* __restrict__ cnt = cntAll + mat;

    __shared__ unsigned short par[NPT];
    const int t = threadIdx.x;

    for (int c = t; c < NPT; c += 1024) {
        unsigned p = (unsigned)c;
        unsigned long long key = compbest[c];
        if (comp[c] == (unsigned)c && key != INF64) {
            unsigned jout = (unsigned)(key & 0xFFFFull);
            unsigned c2 = comp[jout];
            unsigned long long k2 = compbest[c2];
            bool mutual = (k2 >> 16) == (key >> 16);     // same undirected edge (h,mn,mx)
            if (!mutual || (unsigned)c < c2) {
                unsigned short hb = (unsigned short)(key >> 48);
                float wv = fminf(__half2float(__ushort_as_half(hb)), 100.0f);
                unsigned slot = atomicAdd(cnt, 1u);
                w[slot] = wv;
            }
            p = (mutual && (unsigned)c < c2) ? (unsigned)c : c2;
        }
        par[c] = (unsigned short)p;
    }
    __syncthreads();

    // pointer jumping: 12 doublings cover chains up to 4096
    for (int it = 0; it < 12; ++it) {
        unsigned short np[4];
        #pragma unroll
        for (int q = 0; q < 4; ++q) np[q] = par[par[t + q * 1024]];
        __syncthreads();
        #pragma unroll
        for (int q = 0; q < 4; ++q) par[t + q * 1024] = np[q];
        __syncthreads();
    }

    for (int c = t; c < NPT; c += 1024) {
        comp[c] = par[comp[c]];
        compbest[c] = INF64;                             // reset for next round
    }
}

// ---------------- representation loss partial sums ----------------
__global__ __launch_bounds__(256) void rep_kernel(const float4* __restrict__ x1,
                                                  const float4* __restrict__ x2,
                                                  float* __restrict__ acc) {
    int idx = blockIdx.x * blockDim.x + threadIdx.x;
    int stride = gridDim.x * blockDim.x;
    float s = 0.f;
    for (int i = idx; i < NPT * DM / 4; i += stride) {
        float4 a = x1[i], b = x2[i];
        float d0 = a.x - b.x, d1 = a.y - b.y, d2 = a.z - b.z, d3 = a.w - b.w;
        s += d0 * d0 + d1 * d1 + d2 * d2 + d3 * d3;
    }
    #pragma unroll
    for (int off = 32; off > 0; off >>= 1) s += __shfl_down(s, off);
    __shared__ float partial[4];
    int wv = threadIdx.x >> 6, ln = threadIdx.x & 63;
    if (ln == 0) partial[wv] = s;
    __syncthreads();
    if (threadIdx.x == 0) {
        float tot = partial[0] + partial[1] + partial[2] + partial[3];
        atomicAdd(acc, tot);
    }
}

// ---------------- sort both weight arrays (bitonic, LDS), W1 + combine ----------------
__global__ __launch_bounds__(1024) void final_kernel(const float* __restrict__ w1,
                                                     const float* __restrict__ w2,
                                                     const float* __restrict__ rep,
                                                     float* __restrict__ out) {
    __shared__ float s1[NPT];
    __shared__ float s2[NPT];
    const int t = threadIdx.x;
    for (int i = t; i < NPT; i += 1024) { s1[i] = w1[i]; s2[i] = w2[i]; }
    __syncthreads();

    for (int k = 2; k <= NPT; k <<= 1) {
        for (int j = k >> 1; j > 0; j >>= 1) {
            for (int i = t; i < NPT; i += 1024) {
                int ixj = i ^ j;
                if (ixj > i) {
                    bool up = (i & k) == 0;
                    float a = s1[i], b = s1[ixj];
                    if ((a > b) == up) { s1[i] = b; s1[ixj] = a; }
                    float c = s2[i], d = s2[ixj];
                    if ((c > d) == up) { s2[i] = d; s2[ixj] = c; }
                }
            }
            __syncthreads();
        }
    }

    float loc = 0.f;
    for (int i = t; i < NPT; i += 1024) loc += fabsf(s1[i] - s2[i]);
    #pragma unroll
    for (int off = 32; off > 0; off >>= 1) loc += __shfl_down(loc, off);
    __shared__ float reds[16];
    int wv = t >> 6, ln = t & 63;
    if (ln == 0) reds[wv] = loc;
    __syncthreads();
    if (t == 0) {
        float tot = 0.f;
        #pragma unroll
        for (int i = 0; i < 16; ++i) tot += reds[i];
        out[0] = tot + rep[0] * (1.0f / (NPT * DM));
    }
}

extern "C" void kernel_launch(void* const* d_in, const int* in_sizes, int n_in,
                              void* d_out, int out_size, void* d_ws, size_t ws_size,
                              hipStream_t stream) {
    const float* x1 = (const float*)d_in[0];
    const float* x2 = (const float*)d_in[1];
    float* out = (float*)d_out;

    char* ws = (char*)d_ws;
    __half* D = (__half*)ws;                                           // 64 MB
    size_t off = (size_t)2 * NPT * NPT * sizeof(__half);
    unsigned long long* compbest = (unsigned long long*)(ws + off);    // 2*4096*8 = 64 KB
    off += (size_t)2 * NPT * sizeof(unsigned long long);
    float* w = (float*)(ws + off);                                     // 2*4096*4
    off += (size_t)2 * NPT * sizeof(float);
    unsigned* comp = (unsigned*)(ws + off);                            // 2*4096*4
    off += (size_t)2 * NPT * sizeof(unsigned);
    unsigned* cnt = (unsigned*)(ws + off);                             // 2*4
    off += 2 * sizeof(unsigned);
    float* rep = (float*)(ws + off);

    init_kernel<<<2 * NPT / 256, 256, 0, stream>>>(comp, compbest, w, cnt, rep);

    dim3 dg(NPT / 64, NPT / 64, 2);
    dist_kernel<<<dg, 256, 0, stream>>>(x1, x2, D);

    for (int r = 0; r < ROUNDS; ++r) {
        boruvka_a<<<dim3(NPT / 16, 2), 1024, 0, stream>>>(D, comp, compbest);
        boruvka_cd<<<2, 1024, 0, stream>>>(comp, compbest, w, cnt);
    }

    rep_kernel<<<256, 256, 0, stream>>>((const float4*)x1, (const float4*)x2, rep);

    final_kernel<<<1, 1024, 0, stream>>>(w + 0, w + NPT, rep, out);
}

// Round 3
// 341.410 us; speedup vs baseline: 18.9613x; 1.8962x over previous
//
#include <hip/hip_runtime.h>
#include <hip/hip_fp16.h>

#define NPT 4096
#define DM 128
#define ROUNDS 12
#define INF64 0xFFFFFFFFFFFFFFFFull

typedef _Float16 f16x8 __attribute__((ext_vector_type(8)));
typedef _Float16 f16x2 __attribute__((ext_vector_type(2)));
typedef float f32x4 __attribute__((ext_vector_type(4)));

// ---------------- init: comp[i]=i, compbest=INF, w=0, cnt=0, rep=0 ----------------
__global__ __launch_bounds__(256) void init_kernel(unsigned* __restrict__ comp,
                                                   unsigned long long* __restrict__ compbest,
                                                   float* __restrict__ w,
                                                   unsigned* __restrict__ cnt,
                                                   float* __restrict__ rep) {
    int i = blockIdx.x * blockDim.x + threadIdx.x;   // 0..8191
    comp[i] = (unsigned)(i & (NPT - 1));
    compbest[i] = INF64;
    w[i] = 0.0f;
    if (i < 2) cnt[i] = 0u;
    if (i == 0) rep[0] = 0.0f;
}

// ---------------- prep: fp32 -> fp16 rows + consistent squared norms ----------------
__global__ __launch_bounds__(256) void prep_kernel(const float* __restrict__ x1,
                                                   const float* __restrict__ x2,
                                                   _Float16* __restrict__ Xh,
                                                   float* __restrict__ norms) {
    const int wv = threadIdx.x >> 6, ln = threadIdx.x & 63;
    const int row = blockIdx.x * 4 + wv;             // 0..8191
    const float* src = (row < NPT) ? (x1 + (size_t)row * DM)
                                   : (x2 + (size_t)(row - NPT) * DM);
    float2 v = *(const float2*)(src + ln * 2);
    _Float16 h0 = (_Float16)v.x, h1 = (_Float16)v.y;
    f16x2 p; p[0] = h0; p[1] = h1;
    *(f16x2*)(Xh + (size_t)row * DM + ln * 2) = p;
    float a = (float)h0, b = (float)h1;
    float s = a * a + b * b;
    #pragma unroll
    for (int off = 32; off > 0; off >>= 1) s += __shfl_down(s, off);
    if (ln == 0) norms[row] = s;
}

// ---------------- Gram via fp16 MFMA, upper-triangle tiles, D fp16 ----------------
// grid (528, 2), block 256 (4 waves, each 64x64 of a 128x128 tile)
__global__ __launch_bounds__(256) void gram_kernel(const _Float16* __restrict__ Xh,
                                                   const float* __restrict__ norms,
                                                   __half* __restrict__ Dall) {
    const int mat = blockIdx.y;
    const _Float16* __restrict__ X = Xh + (size_t)mat * NPT * DM;
    const float* __restrict__ nrm = norms + mat * NPT;
    __half* __restrict__ D = Dall + (size_t)mat * NPT * NPT;

    // decode upper-tri pair (I <= J) from linear idx = J*(J+1)/2 + I
    int idx = blockIdx.x;
    int J = (int)((sqrtf(8.0f * (float)idx + 1.0f) - 1.0f) * 0.5f);
    while ((J + 1) * (J + 2) / 2 <= idx) ++J;
    while (J * (J + 1) / 2 > idx) --J;
    const int I = idx - J * (J + 1) / 2;

    const int t = threadIdx.x;
    const int wv = t >> 6, ln = t & 63;
    const int rowBase = I * 128 + (wv >> 1) * 64;
    const int colBase = J * 128 + (wv & 1) * 64;
    const int lr = ln & 15;     // lane's row/col within fragment
    const int kg = ln >> 4;     // lane's k-group (8 elems)

    f32x4 acc[4][4];
    #pragma unroll
    for (int m = 0; m < 4; ++m)
        #pragma unroll
        for (int n = 0; n < 4; ++n)
            acc[m][n] = (f32x4){0.f, 0.f, 0.f, 0.f};

    #pragma unroll
    for (int ks = 0; ks < 4; ++ks) {
        const int k0 = ks * 32 + kg * 8;
        f16x8 a[4], b[4];
        #pragma unroll
        for (int m = 0; m < 4; ++m)
            a[m] = *(const f16x8*)(X + (size_t)(rowBase + m * 16 + lr) * DM + k0);
        #pragma unroll
        for (int n = 0; n < 4; ++n)
            b[n] = *(const f16x8*)(X + (size_t)(colBase + n * 16 + lr) * DM + k0);
        #pragma unroll
        for (int m = 0; m < 4; ++m)
            #pragma unroll
            for (int n = 0; n < 4; ++n)
                acc[m][n] = __builtin_amdgcn_mfma_f32_16x16x32_f16(a[m], b[n], acc[m][n], 0, 0, 0);
    }

    float nr[16], nc[4];
    #pragma unroll
    for (int m = 0; m < 4; ++m)
        #pragma unroll
        for (int q = 0; q < 4; ++q)
            nr[m * 4 + q] = nrm[rowBase + m * 16 + kg * 4 + q];
    #pragma unroll
    for (int n = 0; n < 4; ++n) nc[n] = nrm[colBase + n * 16 + lr];

    // C/D layout (verified m89): col = lane&15, row = (lane>>4)*4 + reg
    #pragma unroll
    for (int m = 0; m < 4; ++m) {
        #pragma unroll
        for (int n = 0; n < 4; ++n) {
            #pragma unroll
            for (int q = 0; q < 4; ++q) {
                const int r = rowBase + m * 16 + kg * 4 + q;
                const int c = colBase + n * 16 + lr;
                float d2 = nr[m * 4 + q] + nc[n] - 2.0f * acc[m][n][q];
                float d = sqrtf(fmaxf(d2, 0.0f) + 1e-12f);
                __half hd = __float2half(d);
                D[(size_t)r * NPT + c] = hd;
                if (I != J) D[(size_t)c * NPT + r] = hd;
            }
        }
    }
}

// ---------------- Boruvka phase A: per-node min outgoing edge ----------------
// block = 1024 (16 waves), each wave handles one node; grid (NPT/16, 2)
__global__ __launch_bounds__(1024) void boruvka_a(const __half* __restrict__ Dall,
                                                  const unsigned* __restrict__ compAll,
                                                  unsigned long long* __restrict__ compbestAll,
                                                  const unsigned* __restrict__ cnt) {
    const int mat = blockIdx.y;
    if (cnt[mat] >= NPT - 1u) return;                 // MST complete: no-op round
    const __half* __restrict__ D = Dall + (size_t)mat * NPT * NPT;
    const unsigned* __restrict__ comp = compAll + mat * NPT;
    unsigned long long* __restrict__ compbest = compbestAll + mat * NPT;

    __shared__ unsigned short lcomp[NPT];
    const int t = threadIdx.x;
    for (int i = t; i < NPT; i += 1024) lcomp[i] = (unsigned short)comp[i];
    __syncthreads();

    const int wv = t >> 6, ln = t & 63;
    const int node = blockIdx.x * 16 + wv;
    const unsigned ci = lcomp[node];
    const unsigned* __restrict__ row = (const unsigned*)(D + (size_t)node * NPT);

    unsigned best = 0xFFFFFFFFu;
    #pragma unroll
    for (int k = 0; k < 8; ++k) {
        const int jb = k * 512 + ln * 8;
        uint4 dv = *(const uint4*)(row + (jb >> 1));
        uint4 cv = *(const uint4*)&lcomp[jb];
        const unsigned dp[4] = {dv.x, dv.y, dv.z, dv.w};
        const unsigned cp[4] = {cv.x, cv.y, cv.z, cv.w};
        #pragma unroll
        for (int q = 0; q < 4; ++q) {
            int j0 = jb + q * 2;
            unsigned k0 = (dp[q] << 16) | (unsigned)j0;
            unsigned k1 = (dp[q] & 0xFFFF0000u) | (unsigned)(j0 + 1);
            if ((cp[q] & 0xFFFFu) == ci) k0 = 0xFFFFFFFFu;
            if ((cp[q] >> 16) == ci)     k1 = 0xFFFFFFFFu;
            unsigned m = k0 < k1 ? k0 : k1;
            best = best < m ? best : m;
        }
    }
    #pragma unroll
    for (int off = 32; off > 0; off >>= 1) {
        unsigned o = __shfl_down(best, off);
        best = best < o ? best : o;
    }
    if (ln == 0 && best != 0xFFFFFFFFu) {
        unsigned h = best >> 16;
        unsigned j = best & 0xFFFFu;
        unsigned mn = (unsigned)node < j ? (unsigned)node : j;
        unsigned mx = (unsigned)node < j ? j : (unsigned)node;
        unsigned long long key64 = ((unsigned long long)h << 48) |
                                   ((unsigned long long)mn << 32) |
                                   ((unsigned long long)mx << 16) |
                                   (unsigned long long)j;
        atomicMin(&compbest[ci], key64);
    }
}

// ---------------- Boruvka phase C+D: union, collect weights, pointer-jump, reset ----------------
__global__ __launch_bounds__(1024) void boruvka_cd(unsigned* __restrict__ compAll,
                                                   unsigned long long* __restrict__ compbestAll,
                                                   float* __restrict__ wAll,
                                                   unsigned* __restrict__ cntAll) {
    const int mat = blockIdx.x;
    if (cntAll[mat] >= NPT - 1u) return;
    unsigned* __restrict__ comp = compAll + mat * NPT;
    unsigned long long* __restrict__ compbest = compbestAll + mat * NPT;
    float* __restrict__ w = wAll + mat * NPT;
    unsigned* __restrict__ cnt = cntAll + mat;

    __shared__ unsigned short par[NPT];
    const int t = threadIdx.x;

    for (int c = t; c < NPT; c += 1024) {
        unsigned p = (unsigned)c;
        unsigned long long key = compbest[c];
        if (comp[c] == (unsigned)c && key != INF64) {
            unsigned jout = (unsigned)(key & 0xFFFFull);
            unsigned c2 = comp[jout];
            unsigned long long k2 = compbest[c2];
            bool mutual = (k2 >> 16) == (key >> 16);     // same undirected edge
            if (!mutual || (unsigned)c < c2) {
                unsigned short hb = (unsigned short)(key >> 48);
                float wv = fminf(__half2float(__ushort_as_half(hb)), 100.0f);
                unsigned slot = atomicAdd(cnt, 1u);
                w[slot] = wv;
            }
            p = (mutual && (unsigned)c < c2) ? (unsigned)c : c2;
        }
        par[c] = (unsigned short)p;
    }
    __syncthreads();

    for (int it = 0; it < 12; ++it) {
        unsigned short np[4];
        #pragma unroll
        for (int q = 0; q < 4; ++q) np[q] = par[par[t + q * 1024]];
        __syncthreads();
        #pragma unroll
        for (int q = 0; q < 4; ++q) par[t + q * 1024] = np[q];
        __syncthreads();
    }

    for (int c = t; c < NPT; c += 1024) {
        comp[c] = par[comp[c]];
        compbest[c] = INF64;
    }
}

// ---------------- representation loss partial sums ----------------
__global__ __launch_bounds__(256) void rep_kernel(const float4* __restrict__ x1,
                                                  const float4* __restrict__ x2,
                                                  float* __restrict__ acc) {
    int idx = blockIdx.x * blockDim.x + threadIdx.x;
    int stride = gridDim.x * blockDim.x;
    float s = 0.f;
    for (int i = idx; i < NPT * DM / 4; i += stride) {
        float4 a = x1[i], b = x2[i];
        float d0 = a.x - b.x, d1 = a.y - b.y, d2 = a.z - b.z, d3 = a.w - b.w;
        s += d0 * d0 + d1 * d1 + d2 * d2 + d3 * d3;
    }
    #pragma unroll
    for (int off = 32; off > 0; off >>= 1) s += __shfl_down(s, off);
    __shared__ float partial[4];
    int wv = threadIdx.x >> 6, ln = threadIdx.x & 63;
    if (ln == 0) partial[wv] = s;
    __syncthreads();
    if (threadIdx.x == 0) {
        float tot = partial[0] + partial[1] + partial[2] + partial[3];
        atomicAdd(acc, tot);
    }
}

// ---------------- sort one weight array per block (bitonic, LDS) ----------------
__global__ __launch_bounds__(1024) void sort_kernel(float* __restrict__ wAll) {
    float* __restrict__ w = wAll + blockIdx.x * NPT;
    __shared__ float s[NPT];
    const int t = threadIdx.x;
    for (int i = t; i < NPT; i += 1024) s[i] = w[i];
    __syncthreads();

    for (int k = 2; k <= NPT; k <<= 1) {
        for (int j = k >> 1; j > 0; j >>= 1) {
            for (int i = t; i < NPT; i += 1024) {
                int ixj = i ^ j;
                if (ixj > i) {
                    bool up = (i & k) == 0;
                    float a = s[i], b = s[ixj];
                    if ((a > b) == up) { s[i] = b; s[ixj] = a; }
                }
            }
            __syncthreads();
        }
    }
    for (int i = t; i < NPT; i += 1024) w[i] = s[i];
}

// ---------------- W1 diff-sum + combine ----------------
__global__ __launch_bounds__(1024) void final2_kernel(const float* __restrict__ w,
                                                      const float* __restrict__ rep,
                                                      float* __restrict__ out) {
    const int t = threadIdx.x;
    float loc = 0.f;
    for (int i = t; i < NPT; i += 1024) loc += fabsf(w[i] - w[NPT + i]);
    #pragma unroll
    for (int off = 32; off > 0; off >>= 1) loc += __shfl_down(loc, off);
    __shared__ float reds[16];
    int wv = t >> 6, ln = t & 63;
    if (ln == 0) reds[wv] = loc;
    __syncthreads();
    if (t == 0) {
        float tot = 0.f;
        #pragma unroll
        for (int i = 0; i < 16; ++i) tot += reds[i];
        out[0] = tot + rep[0] * (1.0f / (NPT * DM));
    }
}

extern "C" void kernel_launch(void* const* d_in, const int* in_sizes, int n_in,
                              void* d_out, int out_size, void* d_ws, size_t ws_size,
                              hipStream_t stream) {
    const float* x1 = (const float*)d_in[0];
    const float* x2 = (const float*)d_in[1];
    float* out = (float*)d_out;

    char* ws = (char*)d_ws;
    __half* D = (__half*)ws;                                           // 64 MB
    size_t off = (size_t)2 * NPT * NPT * sizeof(__half);
    _Float16* Xh = (_Float16*)(ws + off);                              // 2 MB
    off += (size_t)2 * NPT * DM * sizeof(_Float16);
    float* norms = (float*)(ws + off);                                 // 32 KB
    off += (size_t)2 * NPT * sizeof(float);
    unsigned long long* compbest = (unsigned long long*)(ws + off);    // 64 KB
    off += (size_t)2 * NPT * sizeof(unsigned long long);
    float* w = (float*)(ws + off);                                     // 32 KB
    off += (size_t)2 * NPT * sizeof(float);
    unsigned* comp = (unsigned*)(ws + off);                            // 32 KB
    off += (size_t)2 * NPT * sizeof(unsigned);
    unsigned* cnt = (unsigned*)(ws + off);                             // 16 B
    off += 4 * sizeof(unsigned);
    float* rep = (float*)(ws + off);

    init_kernel<<<2 * NPT / 256, 256, 0, stream>>>(comp, compbest, w, cnt, rep);

    prep_kernel<<<2 * NPT / 4, 256, 0, stream>>>(x1, x2, Xh, norms);

    gram_kernel<<<dim3(528, 2), 256, 0, stream>>>(Xh, norms, D);

    for (int r = 0; r < ROUNDS; ++r) {
        boruvka_a<<<dim3(NPT / 16, 2), 1024, 0, stream>>>(D, comp, compbest, cnt);
        boruvka_cd<<<2, 1024, 0, stream>>>(comp, compbest, w, cnt);
    }

    rep_kernel<<<256, 256, 0, stream>>>((const float4*)x1, (const float4*)x2, rep);

    sort_kernel<<<2, 1024, 0, stream>>>(w);

    final2_kernel<<<1, 1024, 0, stream>>>(w, rep, out);
}